// Round 4
// baseline (183.138 us; speedup 1.0000x reference)
//
#include <hip/hip_runtime.h>
#include <hip/hip_bf16.h>

// E_s = 0.5 * sum W[a,b,n] A[i,j,n] v[i,a,s] v[j,b,s]
// Refactor: G[(j,n),(a,s)] = sum_b W[a,b,n] v[j,b,s]   (16384 x 192, bf16)
//           r[i,(a,s)]     = sum_{jn} A[i,jn] G[jn,(a,s)]   <- single GEMM, K=16384
//           E_s            = 0.5 * sum_{i,a} v[i,a,s] r[i,(a,s)]
// K-dim (j,n) is A's contiguous order. 8-way K-split mapped to XCDs via bid&7
// so each XCD's L2 holds one 768 KB G-slab.

typedef __attribute__((ext_vector_type(8))) short short8;   // bf16x8 MFMA frag
typedef __attribute__((ext_vector_type(4))) float floatx4;

#define GF_U4 393216   // 12 fragcols * 2048 kb * 16 ci  (6 MB)
#define NBLK  512

__device__ __forceinline__ unsigned pk2(float lo, float hi) {
    __hip_bfloat162 h = __float22bfloat162_rn(make_float2(lo, hi));
    union { __hip_bfloat162 h; unsigned u; } c; c.h = h; return c.u;
}

// Gf layout: [f=c/16][kb=k/8][ci=c%16] uint4 (8 bf16 k-elems for column c).
// c = a*64+s, k = j*4+n.
__global__ void prep_G(const float* __restrict__ W, const float* __restrict__ v,
                       uint4* __restrict__ Gf) {
    __shared__ float Wl[36];
    if (threadIdx.x < 36) Wl[threadIdx.x] = W[threadIdx.x];
    __syncthreads();
    int g = blockIdx.x * 256 + threadIdx.x;   // 1536*256 == GF_U4
    int ci = g & 15;
    int kb = (g >> 4) & 2047;
    int f  = g >> 15;
    int c = f * 16 + ci;
    int a = c >> 6, s = c & 63;
    int j0 = kb * 2;                          // k0 = kb*8 -> j0 = kb*2
    float vv[2][3];
    #pragma unroll
    for (int jj = 0; jj < 2; ++jj)
        #pragma unroll
        for (int b = 0; b < 3; ++b)
            vv[jj][b] = v[((j0 + jj) * 3 + b) * 64 + s];
    float Gv[8];
    #pragma unroll
    for (int e = 0; e < 8; ++e) {
        int n = e & 3, jj = e >> 2;
        Gv[e] = Wl[(a*3+0)*4+n] * vv[jj][0] + Wl[(a*3+1)*4+n] * vv[jj][1]
              + Wl[(a*3+2)*4+n] * vv[jj][2];
    }
    Gf[g] = make_uint4(pk2(Gv[0],Gv[1]), pk2(Gv[2],Gv[3]),
                       pk2(Gv[4],Gv[5]), pk2(Gv[6],Gv[7]));
}

// 512 blocks = 64 i-tiles (64 rows) x 8 k-slabs (2048 k). q = bid&7 -> XCD.
// 512 thr = 8 waves = 4 m-groups x 2 c-slices(96 c). BK=64 -> 32 steps.
// LDS: A 2x8KB bf16 (swizzled) + B 2x24KB frag-linear = 64 KB.
__global__ __launch_bounds__(512, 4) void energy_main(
        const float* __restrict__ A, const float* __restrict__ v,
        const uint4* __restrict__ Gf, float* __restrict__ partials) {
    __shared__ __align__(16) char LdsB[65536];

    const int tid = threadIdx.x;
    const int bid = blockIdx.x;
    const int q  = bid & 7;
    const int it = bid >> 3;
    const int i0 = it * 64;

    const int lane = tid & 63;
    const int w  = tid >> 6;
    const int mg = w >> 1;           // 0..3: rows [mg*16, +16)
    const int cs = w & 1;            // 0..1: cols [cs*96, +96)
    const int rr = lane & 15;

    // ---- A staging: piece p = tid + 512u -> r=p>>4, kq=p&15 (kq same both u)
    const int kq = tid & 15;
    const int r0 = tid >> 4;         // u=0: rows 0..31
    const int r1 = r0 + 32;          // u=1: rows 32..63
    const long aBase0 = (long)(i0 + r0) * 4096 + q * 512 + kq;  // float4 units
    const long aBase1 = (long)(i0 + r1) * 4096 + q * 512 + kq;
    const int aWr0 = r0*128 + (((kq>>1) ^ (r0&7)) << 4) + ((kq&1) << 3); // bytes
    const int aWr1 = r1*128 + (((kq>>1) ^ (r1&7)) << 4) + ((kq&1) << 3);

    // ---- B staging: w4 = tid + 512*u2 -> f=w4>>7, kb=(w4>>4)&7, ci=w4&15
    long bBase[3]; int bWr[3];
    #pragma unroll
    for (int u2 = 0; u2 < 3; ++u2) {
        int w4 = tid + 512 * u2;
        int f = w4 >> 7, kb = (w4 >> 4) & 7, ci = w4 & 15;
        bBase[u2] = (long)(f * 2048 + q * 256 + kb) * 16 + ci; // uint4 units; +t*128
        bWr[u2] = 16384 + w4 * 16;                             // bytes; +bufB*24576
    }

    // ---- frag read offsets
    int aRd[2];
    #pragma unroll
    for (int kk = 0; kk < 2; ++kk)
        aRd[kk] = (mg*16 + rr)*128 + ((((kk<<2) + (lane>>4)) ^ (rr&7)) << 4);
    const int bRdBase = 16384 + (cs * 6) * 2048 + lane * 16;   // + cf*2048 + kk*1024

    floatx4 acc[6];
    #pragma unroll
    for (int cf = 0; cf < 6; ++cf)
        #pragma unroll
        for (int rg = 0; rg < 4; ++rg) acc[cf][rg] = 0.0f;

    const floatx4* A4 = reinterpret_cast<const floatx4*>(A);
    unsigned* L32 = reinterpret_cast<unsigned*>(LdsB);

    auto wrA = [&](int buf, const floatx4& x0, const floatx4& x1) {
        int b0 = buf * 8192;
        L32[(b0 + aWr0) >> 2]     = pk2(x0.x, x0.y);
        L32[(b0 + aWr0) >> 2 + 0] = pk2(x0.x, x0.y); // placeholder removed below
    };
    (void)wrA;

    // ---- prologue: stage tile 0; fill 2-deep register pipeline (tiles 1,2)
    {
        floatx4 a0 = __builtin_nontemporal_load(A4 + aBase0);
        floatx4 a1 = __builtin_nontemporal_load(A4 + aBase1);
        uint4 b0 = Gf[bBase[0]], b1 = Gf[bBase[1]], b2 = Gf[bBase[2]];
        *reinterpret_cast<uint2*>(LdsB + aWr0) = make_uint2(pk2(a0.x,a0.y), pk2(a0.z,a0.w));
        *reinterpret_cast<uint2*>(LdsB + aWr1) = make_uint2(pk2(a1.x,a1.y), pk2(a1.z,a1.w));
        *reinterpret_cast<uint4*>(LdsB + bWr[0]) = b0;
        *reinterpret_cast<uint4*>(LdsB + bWr[1]) = b1;
        *reinterpret_cast<uint4*>(LdsB + bWr[2]) = b2;
    }
    floatx4 pA0[2], pA1[2];
    uint4 pB[2][3];
    #pragma unroll
    for (int ph = 0; ph < 2; ++ph) {      // tiles 1 and 2
        int t = 1 + ph;
        pA0[ph] = __builtin_nontemporal_load(A4 + aBase0 + t * 16);
        pA1[ph] = __builtin_nontemporal_load(A4 + aBase1 + t * 16);
        #pragma unroll
        for (int u2 = 0; u2 < 3; ++u2) pB[ph][u2] = Gf[bBase[u2] + t * 128];
    }

    int cur = 0;
    for (int tt = 0; tt < 32; tt += 2) {
        #pragma unroll
        for (int ph = 0; ph < 2; ++ph) {
            const int t = tt + ph;
            __syncthreads();                    // tile t visible in buf cur
            const char* base = LdsB + cur * 8192;
            const char* bbase = LdsB + cur * 24576 + bRdBase;
            #pragma unroll
            for (int kk = 0; kk < 2; ++kk) {
                short8 af = *reinterpret_cast<const short8*>(base + aRd[kk]);
                #pragma unroll
                for (int cf = 0; cf < 6; ++cf) {
                    short8 bf = *reinterpret_cast<const short8*>(bbase + cf*2048 + kk*1024);
                    acc[cf] = __builtin_amdgcn_mfma_f32_16x16x32_bf16(af, bf, acc[cf], 0, 0, 0);
                }
            }
            __syncthreads();                    // reads of buf cur done
            if (t < 31) {                       // write tile t+1 (regs, set ph)
                char* dstA = LdsB + (cur ^ 1) * 8192;
                char* dst  = LdsB + (cur ^ 1) * 24576;
                *reinterpret_cast<uint2*>(dstA + aWr0) =
                    make_uint2(pk2(pA0[ph].x, pA0[ph].y), pk2(pA0[ph].z, pA0[ph].w));
                *reinterpret_cast<uint2*>(dstA + aWr1) =
                    make_uint2(pk2(pA1[ph].x, pA1[ph].y), pk2(pA1[ph].z, pA1[ph].w));
                *reinterpret_cast<uint4*>(dst + bWr[0]) = pB[ph][0];
                *reinterpret_cast<uint4*>(dst + bWr[1]) = pB[ph][1];
                *reinterpret_cast<uint4*>(dst + bWr[2]) = pB[ph][2];
            }
            if (t < 29) {                       // refill set ph with tile t+3
                const int tn = t + 3;
                pA0[ph] = __builtin_nontemporal_load(A4 + aBase0 + tn * 16);
                pA1[ph] = __builtin_nontemporal_load(A4 + aBase1 + tn * 16);
                #pragma unroll
                for (int u2 = 0; u2 < 3; ++u2) pB[ph][u2] = Gf[bBase[u2] + tn * 128];
            }
            cur ^= 1;
        }
    }

    // ---- epilogue: E_s += acc[i,(a,s)] * v[i,a,s]
    // C layout: col = lane&15, row = (lane>>4)*4 + rg
    float* El = reinterpret_cast<float*>(LdsB);
    __syncthreads();
    if (tid < 64) El[tid] = 0.0f;
    __syncthreads();
    const int rowg = lane >> 4;
    float cont[6];
    #pragma unroll
    for (int cf = 0; cf < 6; ++cf) {
        int c = cs * 96 + cf * 16 + rr;
        int a = c >> 6, s = c & 63;
        float sum = 0.0f;
        #pragma unroll
        for (int rg = 0; rg < 4; ++rg) {
            int i = i0 + mg * 16 + rowg * 4 + rg;
            sum += acc[cf][rg] * v[(i * 3 + a) * 64 + s];
        }
        cont[cf] = sum;
    }
    #pragma unroll
    for (int cf = 0; cf < 6; ++cf) {
        cont[cf] += __shfl_xor(cont[cf], 16);
        cont[cf] += __shfl_xor(cont[cf], 32);
    }
    if (lane < 16) {
        #pragma unroll
        for (int cf = 0; cf < 6; ++cf) {
            int c = cs * 96 + cf * 16 + lane;
            atomicAdd(&El[c & 63], cont[cf]);
        }
    }
    __syncthreads();
    if (tid < 64) partials[bid * 64 + tid] = 0.5f * El[tid];
}

// 512 threads: chunk = tid>>6, s = tid&63; fixed order -> deterministic
__global__ void reduce_out(const float* __restrict__ partials, float* __restrict__ out) {
    __shared__ float red[8][64];
    int tid = threadIdx.x;
    int chunk = tid >> 6, s = tid & 63;
    float a = 0.0f;
    for (int m = 0; m < NBLK / 8; ++m)
        a += partials[((m << 3) + chunk) * 64 + s];
    red[chunk][s] = a;
    __syncthreads();
    if (tid < 64) {
        float t = 0.0f;
        #pragma unroll
        for (int c = 0; c < 8; ++c) t += red[c][tid];
        out[tid] = t;
    }
}

extern "C" void kernel_launch(void* const* d_in, const int* in_sizes, int n_in,
                              void* d_out, int out_size, void* d_ws, size_t ws_size,
                              hipStream_t stream) {
    const float* W = (const float*)d_in[0];   // [3][3][4]
    const float* A = (const float*)d_in[1];   // [4096][4096][4]
    const float* v = (const float*)d_in[2];   // [4096][3][64]
    float* out = (float*)d_out;               // [64] f32
    uint4* Gf = (uint4*)d_ws;                                      // 6 MB
    float* partials = (float*)((char*)d_ws + (size_t)GF_U4 * 16);  // +128 KB

    hipLaunchKernelGGL(prep_G, dim3(GF_U4 / 256), dim3(256), 0, stream, W, v, Gf);
    hipLaunchKernelGGL(energy_main, dim3(NBLK), dim3(512), 0, stream, A, v, Gf, partials);
    hipLaunchKernelGGL(reduce_out, dim3(1), dim3(512), 0, stream, partials, out);
}

// Round 6
// 93.518 us; speedup vs baseline: 1.9583x; 1.9583x over previous
//
#include <hip/hip_runtime.h>
#include <hip/hip_bf16.h>

// E_s = 0.5 * sum W[a,b,n] A[i,j,n] v[i,a,s] v[j,b,s]
// G[(j,n),(a,s)] = sum_b W[a,b,n] v[j,b,s]   (16384 x 192 bf16, 6 MB)
// r[i,(a,s)]     = sum_k A[i,k] G[k,(a,s)]   single GEMM, K = A's contiguous order
// E_s            = 0.5 * sum_{i,a} v[i,a,s] r[i,(a,s)]
// 8-way K-split: q = bid&7 == XCD id (round-robin dispatch) -> each XCD's L2
// holds one 768 KB G-slab. A staged f32 via global_load_lds (async DMA),
// converted to bf16 on LDS->reg read. Pre-swizzled global source (XOR granule)
// keeps LDS linear for the DMA while de-conflicting the MFMA-frag reads.

typedef __attribute__((ext_vector_type(8))) short short8;   // bf16x8 MFMA frag
typedef __attribute__((ext_vector_type(4))) float floatx4;

#define GF_U4 393216   // 12 fragcols * 2048 kb * 16 ci (uint4) = 6 MB
#define NBLK  512

__device__ __forceinline__ unsigned pk2(float lo, float hi) {
    __hip_bfloat162 h = __float22bfloat162_rn(make_float2(lo, hi));
    union { __hip_bfloat162 h; unsigned u; } c; c.h = h; return c.u;
}

// async DMA: 16 B per lane, global (per-lane addr) -> LDS (wave-uniform base,
// HW adds lane*16). AS3 pointer formed by truncating the generic LDS address.
__device__ __forceinline__ void gload16(const void* g, unsigned lds32) {
    __builtin_amdgcn_global_load_lds(
        (const __attribute__((address_space(1))) unsigned*)(uintptr_t)g,
        (__attribute__((address_space(3))) unsigned*)(uintptr_t)lds32, 16, 0, 0);
}

// Gf layout: [f=c/16][kb=k/8][ci=c%16] uint4 (8 bf16 k for column c);
// c = a*64+s, k = j*4+n (A's contiguous order).
__global__ void prep_G(const float* __restrict__ W, const float* __restrict__ v,
                       uint4* __restrict__ Gf) {
    __shared__ float Wl[36];
    if (threadIdx.x < 36) Wl[threadIdx.x] = W[threadIdx.x];
    __syncthreads();
    int g = blockIdx.x * 256 + threadIdx.x;   // 1536*256 == GF_U4
    int ci = g & 15;
    int kb = (g >> 4) & 2047;
    int f  = g >> 15;
    int c = f * 16 + ci;
    int a = c >> 6, s = c & 63;
    int j0 = kb * 2;
    float vv[2][3];
    #pragma unroll
    for (int jj = 0; jj < 2; ++jj)
        #pragma unroll
        for (int b = 0; b < 3; ++b)
            vv[jj][b] = v[((j0 + jj) * 3 + b) * 64 + s];
    float Gv[8];
    #pragma unroll
    for (int e = 0; e < 8; ++e) {
        int n = e & 3, jj = e >> 2;
        Gv[e] = Wl[(a*3+0)*4+n] * vv[jj][0] + Wl[(a*3+1)*4+n] * vv[jj][1]
              + Wl[(a*3+2)*4+n] * vv[jj][2];
    }
    Gf[g] = make_uint4(pk2(Gv[0],Gv[1]), pk2(Gv[2],Gv[3]),
                       pk2(Gv[4],Gv[5]), pk2(Gv[6],Gv[7]));
}

// 512 blocks = 64 i-tiles (64 rows) x 8 k-slabs. 512 thr = 8 waves:
// w = mg*4 + cs*2 + kh (mg,cs,kh in {0,1} x {0,1} x {0,1}, mg = w>>2);
// wave = 32 rows x 96 cols x 32 k per BK=64 step.
// LDS: A f32 2 bufs x [64 rows][64 k] linear (16 KB each), XOR-32B-granule
// swizzle applied on the GLOBAL source address (DMA dest must stay linear).
__global__ __launch_bounds__(512, 2) void energy_main(
        const float* __restrict__ A, const float* __restrict__ v,
        const uint4* __restrict__ Gf, float* __restrict__ partials) {
    __shared__ __align__(16) char LdsA[32768];

    const int tid = threadIdx.x;
    const int bid = blockIdx.x;
    const int q  = bid & 7;
    const int i0 = (bid >> 3) * 64;

    const int lane = tid & 63;
    const int w    = tid >> 6;
    const int mg = w >> 2, cs = (w >> 1) & 1, kh = w & 1;
    const int rr = lane & 15, g4 = lane >> 4;

    const unsigned ldsBase = (unsigned)(uintptr_t)&LdsA[0];

    // ---- A staging (DMA): u=0/1 -> row = w*4 + u*32 + g4, k-quad slot rr.
    // global float4 idx pre-swizzled: ((rr>>1) ^ (row&7))*2 + (rr&1)
    const floatx4* A4 = reinterpret_cast<const floatx4*>(A);
    const floatx4* aSrc[2];
    unsigned aDst[2];
    #pragma unroll
    for (int u = 0; u < 2; ++u) {
        int row = w * 4 + u * 32 + g4;
        aSrc[u] = A4 + ((long)(i0 + row) * 4096 + q * 512
                        + (((rr >> 1) ^ (row & 7)) << 1) + (rr & 1));
        aDst[u] = ldsBase + w * 1024 + u * 8192;   // buf0; HW adds lane*16
    }

    // ---- A frag read: row R = mg*32 + rf*16 + rr; 32B granule Gg = kh*4+g4
    // stored at slot Gg ^ (R&7)
    int aRd[2];
    #pragma unroll
    for (int rf = 0; rf < 2; ++rf) {
        int R = mg * 32 + rf * 16 + rr;
        aRd[rf] = R * 256 + (((kh * 4 + g4) ^ (R & 7)) << 5);
    }

    // ---- B pointers: f = cs*6+cf, kb = q*256 + kh*4 + g4 (+8 per step)
    const uint4* gfp[6];
    #pragma unroll
    for (int cf = 0; cf < 6; ++cf) {
        int f = cs * 6 + cf;
        gfp[cf] = Gf + ((long)(f * 2048 + q * 256 + kh * 4 + g4) * 16 + rr);
    }

    floatx4 acc[2][6];
    #pragma unroll
    for (int rf = 0; rf < 2; ++rf)
        #pragma unroll
        for (int cf = 0; cf < 6; ++cf)
            #pragma unroll
            for (int rg = 0; rg < 4; ++rg) acc[rf][cf][rg] = 0.0f;

    // ---- prologue: DMA tile 0 into buf 0
    #pragma unroll
    for (int u = 0; u < 2; ++u) { gload16(aSrc[u], aDst[u]); aSrc[u] += 16; }
    __syncthreads();

    unsigned bufOff = 0;
    for (int t = 0; t < 32; ++t) {
        // B frags for step t (issued FIRST so the MFMA's vmcnt wait on bf[]
        // retires without draining the A-prefetch DMAs behind them)
        short8 bf[6];
        #pragma unroll
        for (int cf = 0; cf < 6; ++cf) {
            bf[cf] = *reinterpret_cast<const short8*>(gfp[cf]);
            gfp[cf] += 128;
        }
        // async-prefetch tile t+1 into the OTHER buffer
        if (t < 31) {
            #pragma unroll
            for (int u = 0; u < 2; ++u) {
                gload16(aSrc[u], aDst[u] + (bufOff ^ 16384));
                aSrc[u] += 16;
            }
        }
        // A frags from LDS (f32 -> bf16 on read)
        short8 af[2];
        #pragma unroll
        for (int rf = 0; rf < 2; ++rf) {
            const char* p = LdsA + (bufOff + aRd[rf]);
            floatx4 x0 = *reinterpret_cast<const floatx4*>(p);
            floatx4 x1 = *reinterpret_cast<const floatx4*>(p + 16);
            union { short8 s; unsigned u[4]; } cv;
            cv.u[0] = pk2(x0.x, x0.y); cv.u[1] = pk2(x0.z, x0.w);
            cv.u[2] = pk2(x1.x, x1.y); cv.u[3] = pk2(x1.z, x1.w);
            af[rf] = cv.s;
        }
        #pragma unroll
        for (int cf = 0; cf < 6; ++cf)
            #pragma unroll
            for (int rf = 0; rf < 2; ++rf)
                acc[rf][cf] = __builtin_amdgcn_mfma_f32_16x16x32_bf16(
                    af[rf], bf[cf], acc[rf][cf], 0, 0, 0);
        __syncthreads();   // vmcnt(0)+barrier: publishes buf^1, reads of buf done
        bufOff ^= 16384;
    }

    // ---- epilogue: E_s += acc[i,(a,s)] * v[i,a,s]
    // C layout: col = lane&15, row = (lane>>4)*4 + rg
    float* El = reinterpret_cast<float*>(LdsA);
    if (tid < 64) El[tid] = 0.0f;
    __syncthreads();
    float cont[6];
    #pragma unroll
    for (int cf = 0; cf < 6; ++cf) {
        int c = cs * 96 + cf * 16 + rr;
        int a = c >> 6, s = c & 63;
        float sum = 0.0f;
        #pragma unroll
        for (int rf = 0; rf < 2; ++rf)
            #pragma unroll
            for (int rg = 0; rg < 4; ++rg) {
                int i = i0 + mg * 32 + rf * 16 + g4 * 4 + rg;
                sum += acc[rf][cf][rg] * v[(i * 3 + a) * 64 + s];
            }
        cont[cf] = sum;
    }
    #pragma unroll
    for (int cf = 0; cf < 6; ++cf) {           // reduce over g4 groups
        cont[cf] += __shfl_xor(cont[cf], 16);
        cont[cf] += __shfl_xor(cont[cf], 32);
    }
    if (lane < 16) {
        #pragma unroll
        for (int cf = 0; cf < 6; ++cf) {
            int c = cs * 96 + cf * 16 + lane;
            atomicAdd(&El[c & 63], cont[cf]);  // LDS, block-local
        }
    }
    __syncthreads();
    if (tid < 64) partials[bid * 64 + tid] = 0.5f * El[tid];
}

// 512 threads: chunk = tid>>6, s = tid&63; fixed order -> deterministic
__global__ void reduce_out(const float* __restrict__ partials, float* __restrict__ out) {
    __shared__ float red[8][64];
    int tid = threadIdx.x;
    int chunk = tid >> 6, s = tid & 63;
    float a = 0.0f;
    for (int m = 0; m < NBLK / 8; ++m)
        a += partials[((m << 3) + chunk) * 64 + s];
    red[chunk][s] = a;
    __syncthreads();
    if (tid < 64) {
        float t = 0.0f;
        #pragma unroll
        for (int c = 0; c < 8; ++c) t += red[c][tid];
        out[tid] = t;
    }
}

extern "C" void kernel_launch(void* const* d_in, const int* in_sizes, int n_in,
                              void* d_out, int out_size, void* d_ws, size_t ws_size,
                              hipStream_t stream) {
    const float* W = (const float*)d_in[0];   // [3][3][4]
    const float* A = (const float*)d_in[1];   // [4096][4096][4]
    const float* v = (const float*)d_in[2];   // [4096][3][64]
    float* out = (float*)d_out;               // [64] f32
    uint4* Gf = (uint4*)d_ws;                                      // 6 MB
    float* partials = (float*)((char*)d_ws + (size_t)GF_U4 * 16);  // +128 KB

    hipLaunchKernelGGL(prep_G, dim3(GF_U4 / 256), dim3(256), 0, stream, W, v, Gf);
    hipLaunchKernelGGL(energy_main, dim3(NBLK), dim3(512), 0, stream, A, v, Gf, partials);
    hipLaunchKernelGGL(reduce_out, dim3(1), dim3(512), 0, stream, partials, out);
}